// Round 2
// 252.684 us; speedup vs baseline: 1.1230x; 1.1230x over previous
//
#include <hip/hip_runtime.h>

#define B_ 4
#define T_ 4096
#define C_ 1024
#define H_ 128

typedef __attribute__((ext_vector_type(8))) __bf16 bf16x8;
typedef __attribute__((ext_vector_type(8))) unsigned short u16x8;
typedef __attribute__((ext_vector_type(4))) float f32x4;

__device__ __forceinline__ unsigned short f2bf(float f) {
  unsigned int u = __float_as_uint(f);
  return (unsigned short)((u + 0x7FFFu + ((u >> 16) & 1u)) >> 16);
}
__device__ __forceinline__ float bf2f(unsigned short h) {
  return __uint_as_float((unsigned)h << 16);
}
__device__ __forceinline__ bf16x8 ldb8(const unsigned short* p) {
  return *(const bf16x8*)(const void*)p;
}
// async global->LDS DMA: 16B/lane, LDS dest = wave-uniform base + lane*16
__device__ __forceinline__ void async16(void* lds, const void* g) {
  __builtin_amdgcn_global_load_lds(
      (const __attribute__((address_space(1))) unsigned int*)g,
      (__attribute__((address_space(3))) unsigned int*)lds, 16, 0, 0);
}
__device__ __forceinline__ void split8a(const float* f, bf16x8& hi, bf16x8& lo) {
  u16x8 h, l;
#pragma unroll
  for (int j = 0; j < 8; j++) {
    h[j] = f2bf(f[j]);
    l[j] = f2bf(f[j] - bf2f(h[j]));
  }
  hi = __builtin_bit_cast(bf16x8, h);
  lo = __builtin_bit_cast(bf16x8, l);
}

// Fragment-ordered K/V global layouts (per batch, elem offsets):
//   K(t,h): kt=t>>6 n=(t>>4)&3 lk=t&15 kk=h>>5 qk=(h>>3)&3 e=h&7
//           off = ((kt*16+n*4+kk)*64 + qk*16+lk)*8 + e
//   V(t,h): kt=t>>6 ks=(t>>5)&1 qv=(t>>3)&3 j=t&7 nv=h>>4 lv=h&15
//           off = ((kt*16+ks*8+nv)*64 + qv*16+lv)*8 + j
// => a 32-row KV chunk kt32 is elems [kt32*4096, kt32*4096+4096): CONTIGUOUS.
//    flash2 stages it into LDS as a linear 8KB copy (6 x async16/thread for
//    Khi+Klo+V) and reads fragments at frag*1KB + lane*16B (conflict-free).

// ---------------------------------------------------------------------------
// Kernel 1: W [C][H] fp32 -> Wthi/Wtlo [.][H][C] bf16, transpose + split,
// with 16B chunks rotated by (h&7) inside each 64-elem k-window so qkv's
// flat global_load_lds staging lands LDS-bank-uniform.   (unchanged)
// ---------------------------------------------------------------------------
__global__ void wt_k(const float* __restrict__ Wq, const float* __restrict__ Wk,
                     const float* __restrict__ Wv, unsigned short* __restrict__ Whi,
                     unsigned short* __restrict__ Wlo) {
  __shared__ float tile[32][33];
  int m = blockIdx.z;
  const float* W = (m == 0) ? Wq : ((m == 1) ? Wk : Wv);
  int c0 = blockIdx.x * 32, h0 = blockIdx.y * 32;
  int tx = threadIdx.x, ty = threadIdx.y;  // 32 x 8
#pragma unroll
  for (int i = 0; i < 4; i++)
    tile[ty + 8 * i][tx] = W[(size_t)(c0 + ty + 8 * i) * H_ + h0 + tx];
  __syncthreads();
  size_t base = (size_t)m * H_ * C_;
#pragma unroll
  for (int i = 0; i < 4; i++) {
    float f = tile[tx][ty + 8 * i];
    unsigned short hi = f2bf(f);
    int h = h0 + ty + 8 * i;
    int kg = c0 + tx;
    int w0 = kg >> 6, c = (kg >> 3) & 7, e = kg & 7;
    size_t idx = base + (size_t)h * C_ + w0 * 64 + ((c + (h & 7)) & 7) * 8 + e;
    Whi[idx] = hi;
    if (m < 2) Wlo[idx] = f2bf(f - bf2f(hi));
  }
}

// ---------------------------------------------------------------------------
// Kernel 2: fused QKV projection, BK=64.  (unchanged)
// ---------------------------------------------------------------------------
__global__ __launch_bounds__(256, 3) void qkv_k(
    const float* __restrict__ x, const unsigned short* __restrict__ Whi,
    const unsigned short* __restrict__ Wlo, unsigned short* __restrict__ Qhi,
    unsigned short* __restrict__ Qlo, unsigned short* __restrict__ Khf,
    unsigned short* __restrict__ Klf, unsigned short* __restrict__ Vf) {
  int m = blockIdx.x % 3;
  int r0 = (blockIdx.x / 3) * 64;
  __shared__ __align__(16) float sx[64 * 64];            // 16 KB, row=256B swizzled
  __shared__ __align__(16) unsigned short swh[128 * 64]; // 16 KB, row=128B swizzled
  __shared__ __align__(16) unsigned short swl[128 * 64]; // 16 KB
  int tid = threadIdx.x;
  int lane = tid & 63, wave = tid >> 6;
  int l15 = lane & 15, quad = lane >> 4;
  const unsigned short* Wmh = Whi + (size_t)m * H_ * C_;
  const unsigned short* Wml = Wlo + (size_t)m * H_ * C_;
  f32x4 acc[8];
#pragma unroll
  for (int n = 0; n < 8; n++) acc[n] = (f32x4){0.f, 0.f, 0.f, 0.f};

  for (int k0 = 0; k0 < C_; k0 += 64) {
    __syncthreads();  // prior iter's LDS reads done
#pragma unroll
    for (int i = 0; i < 4; i++) {
      int s = (wave * 4 + i) * 64 + lane;
      {  // x: LDS slot (tr,p) <- x[r0+tr][k0 + ((p-tr)&15)*4]  (rotated gather)
        int tr = s >> 4, p = s & 15;
        async16((unsigned short*)sx + (size_t)(wave * 4 + i) * 512,
                x + (size_t)(r0 + tr) * C_ + k0 + ((p - tr) & 15) * 4);
      }
      {  // W: flat copy (global already rotated by wt_k)
        int hr = s >> 3, p = s & 7;
        async16(swh + (size_t)(wave * 4 + i) * 512,
                Wmh + (size_t)hr * C_ + k0 + p * 8);
        if (m < 2)
          async16(swl + (size_t)(wave * 4 + i) * 512,
                  Wml + (size_t)hr * C_ + k0 + p * 8);
      }
    }
    __syncthreads();  // barrier drains vmcnt -> staging visible
#pragma unroll
    for (int kk = 0; kk < 2; kk++) {
      float xa[8];
#pragma unroll
      for (int half = 0; half < 2; half++) {
        int p = (kk * 8 + quad * 2 + half + l15) & 15;
        *(f32x4*)&xa[half * 4] =
            *(const f32x4*)(const void*)(sx + (wave * 16 + l15) * 64 + p * 4);
      }
      bf16x8 ahi, alo;
      split8a(xa, ahi, alo);
      if (m < 2) {
#pragma unroll
        for (int n = 0; n < 8; n++) {
          int p = (kk * 4 + quad + l15) & 7;
          bf16x8 bhi = ldb8(swh + (n * 16 + l15) * 64 + p * 8);
          bf16x8 blo = ldb8(swl + (n * 16 + l15) * 64 + p * 8);
          acc[n] = __builtin_amdgcn_mfma_f32_16x16x32_bf16(ahi, bhi, acc[n], 0, 0, 0);
          acc[n] = __builtin_amdgcn_mfma_f32_16x16x32_bf16(alo, bhi, acc[n], 0, 0, 0);
          acc[n] = __builtin_amdgcn_mfma_f32_16x16x32_bf16(ahi, blo, acc[n], 0, 0, 0);
        }
      } else {
#pragma unroll
        for (int n = 0; n < 8; n++) {
          int p = (kk * 4 + quad + l15) & 7;
          bf16x8 bhi = ldb8(swh + (n * 16 + l15) * 64 + p * 8);
          acc[n] = __builtin_amdgcn_mfma_f32_16x16x32_bf16(ahi, bhi, acc[n], 0, 0, 0);
        }
      }
    }
  }
  // epilogue: C-layout row = quad*4+r, col = n8*16+l15
  int ob = r0 + wave * 16 + quad * 4;
  if (m == 0) {  // Q: linear hi/lo
#pragma unroll
    for (int n8 = 0; n8 < 8; n8++)
#pragma unroll
      for (int r = 0; r < 4; r++) {
        float f = acc[n8][r];
        unsigned short hi = f2bf(f);
        size_t idx = (size_t)(ob + r) * H_ + n8 * 16 + l15;
        Qhi[idx] = hi;
        Qlo[idx] = f2bf(f - bf2f(hi));
      }
  } else if (m == 1) {  // K: fragment order hi/lo
#pragma unroll
    for (int n8 = 0; n8 < 8; n8++)
#pragma unroll
      for (int r = 0; r < 4; r++) {
        int gr = ob + r;
        int bb = gr >> 12, t = gr & (T_ - 1);
        int kt = t >> 6, tr = t & 63, nf = tr >> 4, lk = tr & 15;
        int h = n8 * 16 + l15;
        int kkf = h >> 5, qk = (h >> 3) & 3, e = h & 7;
        size_t idx = (size_t)bb * T_ * H_ +
                     (size_t)((kt * 16 + nf * 4 + kkf) * 64 + qk * 16 + lk) * 8 + e;
        float f = acc[n8][r];
        unsigned short hi = f2bf(f);
        Khf[idx] = hi;
        Klf[idx] = f2bf(f - bf2f(hi));
      }
  } else {  // V: fragment order
#pragma unroll
    for (int n8 = 0; n8 < 8; n8++)
#pragma unroll
      for (int r = 0; r < 4; r++) {
        int gr = ob + r;
        int bb = gr >> 12, t = gr & (T_ - 1);
        int kt = t >> 6, ks = (t >> 5) & 1, qv = (t >> 3) & 3, jj = t & 7;
        size_t idx = (size_t)bb * T_ * H_ +
                     (size_t)((kt * 16 + ks * 8 + n8) * 64 + qv * 16 + l15) * 8 + jj;
        Vf[idx] = f2bf(acc[n8][r]);
      }
  }
}

// ---------------------------------------------------------------------------
// Kernel 3: flash attention, shared-KV LDS pipeline + grid split-KV.
//  - block = 64 Q rows (wave w owns rows w*16..w*16+15; no intra-block combine)
//  - KV step = 32 rows; tile (Khi+Klo+V = 24KB) staged via global_load_lds
//    into double-buffered LDS shared by all 4 waves (4x traffic cut vs R7)
//  - counted vmcnt(6): next tile's DMA stays in flight across the whole
//    compute phase (never drain to 0 in the loop)  [T3+T4]
//  - grid split-KV s=2: split 0 = chunks [0,p], split 1 = [p+1,2p+1]
//    (both exactly p+1 iters -> perfectly balanced). Partials (o,m,l) to ws,
//    merged by comb_k.  blockIdx&7 = (batch,split) keeps per-XCD K/V at 3MB.
// ---------------------------------------------------------------------------
#define PP2 40  // per-wave P-buffer pitch (u16): 16 rows x 32 cols + pad
__global__ __launch_bounds__(256, 2) void flash2_k(
    const unsigned short* __restrict__ Qhi, const unsigned short* __restrict__ Qlo,
    const unsigned short* __restrict__ Khf, const unsigned short* __restrict__ Klf,
    const unsigned short* __restrict__ Vf, float* __restrict__ opart,
    float2* __restrict__ mlpart) {
  __shared__ __align__(16) unsigned short skh[2][4096];  // 16 KB Khi dbuf
  __shared__ __align__(16) unsigned short skl[2][4096];  // 16 KB Klo dbuf
  __shared__ __align__(16) unsigned short sv[2][4096];   // 16 KB V   dbuf
  __shared__ __align__(16) unsigned short pb[4][16 * PP2];  // 5 KB P bufs
  int tid = threadIdx.x;
  int wave = tid >> 6, lane = tid & 63;
  int l15 = lane & 15, quad = lane >> 4;

  int g = blockIdx.x & 7;        // XCD-aligned: (batch, split)
  int j = blockIdx.x >> 3;       // 0..63, longest-first
  int b = g >> 1, sp = g & 1;
  int p = 63 - j;                // 64-row q-tile index
  int q0 = p << 6;
  int ktB = sp ? (p + 1) : 0;    // first 32-row KV chunk
  int nt = p + 1;                // chunks in this split
  size_t boff = (size_t)b * T_ * H_;
  const unsigned short* Khb = Khf + boff;
  const unsigned short* Klb = Klf + boff;
  const unsigned short* Vb = Vf + boff;

  // Q fragments for this wave's 16 rows
  bf16x8 qh[4], ql[4];
  {
    const unsigned short* qrh =
        Qhi + boff + (size_t)(q0 + wave * 16 + l15) * H_ + quad * 8;
    const unsigned short* qrl =
        Qlo + boff + (size_t)(q0 + wave * 16 + l15) * H_ + quad * 8;
#pragma unroll
    for (int kk = 0; kk < 4; kk++) {
      qh[kk] = ldb8(qrh + kk * 32);
      ql[kk] = ldb8(qrl + kk * 32);
    }
  }
  f32x4 o[8];
#pragma unroll
  for (int n = 0; n < 8; n++) o[n] = (f32x4){0.f, 0.f, 0.f, 0.f};
  float mr[4] = {-1e30f, -1e30f, -1e30f, -1e30f};
  float lr[4] = {0.f, 0.f, 0.f, 0.f};

  int rmin = q0 + wave * 16;  // wave's first row
  unsigned short* pbw = pb[wave];
  int ch = wave * 2;  // this wave's 2 staging chunks (of 8)

  // stage 32-row KV chunk kt32 into buffer d: 6 x 1KB DMA per wave
#define STAGE(kt32_, d_)                                                        \
  {                                                                             \
    size_t gbase = (size_t)(kt32_)*4096 + (size_t)ch * 512 + (size_t)lane * 8;  \
    async16(&skh[d_][ch * 512], Khb + gbase);                                   \
    async16(&skh[d_][(ch + 1) * 512], Khb + gbase + 512);                       \
    async16(&skl[d_][ch * 512], Klb + gbase);                                   \
    async16(&skl[d_][(ch + 1) * 512], Klb + gbase + 512);                       \
    async16(&sv[d_][ch * 512], Vb + gbase);                                     \
    async16(&sv[d_][(ch + 1) * 512], Vb + gbase + 512);                         \
  }

  STAGE(ktB, 0);
  int cur = 0;
  for (int it = 0; it < nt; ++it) {
    int kt32 = ktB + it;
    if (it + 1 < nt) {
      STAGE(kt32 + 1, cur ^ 1);  // issue next tile (6 loads stay in flight)
      asm volatile("s_waitcnt vmcnt(6)" ::: "memory");  // current tile done
    } else {
      asm volatile("s_waitcnt vmcnt(0)" ::: "memory");
    }
    __builtin_amdgcn_s_barrier();  // staging visible to all waves
    int c0 = kt32 << 5;
    if (c0 <= rmin + 15) {  // wave has unmasked rows in this chunk
      f32x4 s[2];
#pragma unroll
      for (int n16 = 0; n16 < 2; ++n16) s[n16] = (f32x4){0.f, 0.f, 0.f, 0.f};
#pragma unroll
      for (int n16 = 0; n16 < 2; ++n16) {
        bf16x8 kh[4], kl[4];
#pragma unroll
        for (int kk = 0; kk < 4; kk++) {
          kh[kk] = ldb8(&skh[cur][(n16 * 4 + kk) * 512 + lane * 8]);
          kl[kk] = ldb8(&skl[cur][(n16 * 4 + kk) * 512 + lane * 8]);
        }
#pragma unroll
        for (int kk = 0; kk < 4; kk++) {
          s[n16] = __builtin_amdgcn_mfma_f32_16x16x32_bf16(qh[kk], kh[kk], s[n16], 0, 0, 0);
          s[n16] = __builtin_amdgcn_mfma_f32_16x16x32_bf16(ql[kk], kh[kk], s[n16], 0, 0, 0);
          s[n16] = __builtin_amdgcn_mfma_f32_16x16x32_bf16(qh[kk], kl[kk], s[n16], 0, 0, 0);
        }
      }
      if (c0 + 31 > rmin) {  // diagonal chunk: causal mask
#pragma unroll
        for (int n16 = 0; n16 < 2; ++n16) {
          int col = c0 + n16 * 16 + l15;
#pragma unroll
          for (int r = 0; r < 4; r++)
            if (col > rmin + quad * 4 + r) s[n16][r] = -1e30f;
        }
      }
      float mnew[4];
#pragma unroll
      for (int r = 0; r < 4; r++) mnew[r] = fmaxf(s[0][r], s[1][r]);
#pragma unroll
      for (int off = 1; off < 16; off <<= 1)
#pragma unroll
        for (int r = 0; r < 4; r++) mnew[r] = fmaxf(mnew[r], __shfl_xor(mnew[r], off));
      float alpha[4];
#pragma unroll
      for (int r = 0; r < 4; r++) {
        float mi = fmaxf(mr[r], mnew[r]);
        alpha[r] = __expf(mr[r] - mi);
        mr[r] = mi;
      }
      float rs[4];
#pragma unroll
      for (int n16 = 0; n16 < 2; ++n16)
#pragma unroll
        for (int r = 0; r < 4; r++) s[n16][r] = __expf(s[n16][r] - mr[r]);
#pragma unroll
      for (int r = 0; r < 4; r++) rs[r] = s[0][r] + s[1][r];
#pragma unroll
      for (int off = 1; off < 16; off <<= 1)
#pragma unroll
        for (int r = 0; r < 4; r++) rs[r] += __shfl_xor(rs[r], off);
#pragma unroll
      for (int r = 0; r < 4; r++) lr[r] = lr[r] * alpha[r] + rs[r];
#pragma unroll
      for (int n = 0; n < 8; n++)
#pragma unroll
        for (int r = 0; r < 4; r++) o[n][r] *= alpha[r];
      // P: C-layout -> A-layout via wave-private LDS (lgkm ordering suffices)
      asm volatile("s_waitcnt lgkmcnt(0)" ::: "memory");
#pragma unroll
      for (int n16 = 0; n16 < 2; ++n16)
#pragma unroll
        for (int r = 0; r < 4; r++)
          pbw[(quad * 4 + r) * PP2 + n16 * 16 + l15] = f2bf(s[n16][r]);
      asm volatile("s_waitcnt lgkmcnt(0)" ::: "memory");
      bf16x8 pa = ldb8(pbw + l15 * PP2 + quad * 8);  // k=32 A-fragment
#pragma unroll
      for (int nv = 0; nv < 8; ++nv) {
        bf16x8 vf = ldb8(&sv[cur][nv * 512 + lane * 8]);
        o[nv] = __builtin_amdgcn_mfma_f32_16x16x32_bf16(pa, vf, o[nv], 0, 0, 0);
      }
    }
    __builtin_amdgcn_s_barrier();  // all waves done reading buf before reuse
    cur ^= 1;
  }
#undef STAGE

  // epilogue: unnormalized partials to workspace
  size_t obase = (size_t)((b * 64 + p) * 2 + sp) * (64 * 128);
  int wr = wave * 16 + quad * 4;
#pragma unroll
  for (int n = 0; n < 8; n++)
#pragma unroll
    for (int r = 0; r < 4; r++)
      opart[obase + (size_t)(wr + r) * 128 + n * 16 + l15] = o[n][r];
  if (l15 == 0) {
    size_t mbase = (size_t)((b * 64 + p) * 2 + sp) * 64;
#pragma unroll
    for (int r = 0; r < 4; r++)
      mlpart[mbase + wr + r] = make_float2(mr[r], lr[r]);
  }
}

// ---------------------------------------------------------------------------
// Kernel 4: merge the two KV-splits. One thread = 8 output cols.
// ---------------------------------------------------------------------------
__global__ __launch_bounds__(256) void comb_k(const float* __restrict__ opart,
                                              const float2* __restrict__ mlpart,
                                              float* __restrict__ out) {
  int gid = blockIdx.x * 256 + threadIdx.x;  // 0 .. B*T*16-1
  int row = gid >> 4;
  int c0 = (gid & 15) << 3;
  int b = row >> 12, t = row & (T_ - 1);
  int p = t >> 6, r = t & 63;
  size_t mi = (size_t)(b * 64 + p) * 2 * 64 + r;
  float2 ml0 = mlpart[mi], ml1 = mlpart[mi + 64];
  float M = fmaxf(ml0.x, ml1.x);
  float w0 = __expf(ml0.x - M), w1 = __expf(ml1.x - M);
  float invL = 1.0f / (w0 * ml0.y + w1 * ml1.y);
  size_t o0 = ((size_t)(b * 64 + p) * 2 * 64 + r) * 128 + c0;
  size_t o1 = o0 + 64 * 128;
  f32x4 a0 = *(const f32x4*)(const void*)(opart + o0) * w0 +
             *(const f32x4*)(const void*)(opart + o1) * w1;
  f32x4 a1 = *(const f32x4*)(const void*)(opart + o0 + 4) * w0 +
             *(const f32x4*)(const void*)(opart + o1 + 4) * w1;
  float* op = out + ((size_t)b * T_ + t) * H_ + c0;
  *(f32x4*)(void*)op = a0 * invL;
  *(f32x4*)(void*)(op + 4) = a1 * invL;
}

// ---------------------------------------------------------------------------
extern "C" void kernel_launch(void* const* d_in, const int* in_sizes, int n_in,
                              void* d_out, int out_size, void* d_ws, size_t ws_size,
                              hipStream_t stream) {
  const float* x  = (const float*)d_in[0];
  const float* Wq = (const float*)d_in[1];
  const float* Wk = (const float*)d_in[2];
  const float* Wv = (const float*)d_in[3];
  const size_t BTH = (size_t)B_ * T_ * H_;
  unsigned short* Whi = (unsigned short*)d_ws;   // 3*H*C
  unsigned short* Wlo = Whi + 3 * H_ * C_;       // 2*H*C (Q,K only)
  unsigned short* Vf  = Wlo + 2 * H_ * C_;       // BTH
  unsigned short* Qhi = Vf + BTH;
  unsigned short* Qlo = Qhi + BTH;
  unsigned short* Khf = Qlo + BTH;
  unsigned short* Klf = Khf + BTH;
  float* opart = (float*)(void*)(Klf + BTH);           // B*64*2*64*128 f32 (16.8MB)
  float2* mlpart = (float2*)(void*)(opart + (size_t)B_ * 64 * 2 * 64 * 128);
  float* out = (float*)d_out;

  wt_k<<<dim3(32, 4, 3), dim3(32, 8), 0, stream>>>(Wq, Wk, Wv, Whi, Wlo);
  qkv_k<<<3 * (B_ * T_ / 64), 256, 0, stream>>>(x, Whi, Wlo, Qhi, Qlo, Khf, Klf, Vf);
  flash2_k<<<512, 256, 0, stream>>>(Qhi, Qlo, Khf, Klf, Vf, opart, mlpart);
  comb_k<<<(B_ * T_ * 16) / 256, 256, 0, stream>>>(opart, mlpart, out);
}

// Round 3
// 239.500 us; speedup vs baseline: 1.1848x; 1.0550x over previous
//
#include <hip/hip_runtime.h>

#define B_ 4
#define T_ 4096
#define C_ 1024
#define H_ 128

typedef __attribute__((ext_vector_type(8))) __bf16 bf16x8;
typedef __attribute__((ext_vector_type(8))) unsigned short u16x8;
typedef __attribute__((ext_vector_type(4))) float f32x4;

__device__ __forceinline__ unsigned short f2bf(float f) {
  unsigned int u = __float_as_uint(f);
  return (unsigned short)((u + 0x7FFFu + ((u >> 16) & 1u)) >> 16);
}
__device__ __forceinline__ float bf2f(unsigned short h) {
  return __uint_as_float((unsigned)h << 16);
}
__device__ __forceinline__ bf16x8 ldb8(const unsigned short* p) {
  return *(const bf16x8*)(const void*)p;
}
// async global->LDS DMA: 16B/lane, LDS dest = wave-uniform base + lane*16
__device__ __forceinline__ void async16(void* lds, const void* g) {
  __builtin_amdgcn_global_load_lds(
      (const __attribute__((address_space(1))) unsigned int*)g,
      (__attribute__((address_space(3))) unsigned int*)lds, 16, 0, 0);
}
__device__ __forceinline__ void split8a(const float* f, bf16x8& hi, bf16x8& lo) {
  u16x8 h, l;
#pragma unroll
  for (int j = 0; j < 8; j++) {
    h[j] = f2bf(f[j]);
    l[j] = f2bf(f[j] - bf2f(h[j]));
  }
  hi = __builtin_bit_cast(bf16x8, h);
  lo = __builtin_bit_cast(bf16x8, l);
}

// Fragment-ordered K/V global layouts (per batch, elem offsets):
//   K(t,h): kt=t>>6 n=(t>>4)&3 lk=t&15 kk=h>>5 qk=(h>>3)&3 e=h&7
//           off = ((kt*16+n*4+kk)*64 + qk*16+lk)*8 + e
//   V(t,h): kt=t>>6 ks=(t>>5)&1 qv=(t>>3)&3 j=t&7 nv=h>>4 lv=h&15
//           off = ((kt*16+ks*8+nv)*64 + qv*16+lv)*8 + j
// => a 32-row KV chunk kt32 is elems [kt32*4096, kt32*4096+4096): CONTIGUOUS.
//    flash3 stages it into LDS as a linear 8KB copy (6 x async16/thread for
//    Khi+Klo+V) and reads fragments at frag*1KB + lane*16B (conflict-free).

// ---------------------------------------------------------------------------
// Kernel 1: W [C][H] fp32 -> Wthi/Wtlo [.][H][C] bf16, transpose + split.
// (unchanged)
// ---------------------------------------------------------------------------
__global__ void wt_k(const float* __restrict__ Wq, const float* __restrict__ Wk,
                     const float* __restrict__ Wv, unsigned short* __restrict__ Whi,
                     unsigned short* __restrict__ Wlo) {
  __shared__ float tile[32][33];
  int m = blockIdx.z;
  const float* W = (m == 0) ? Wq : ((m == 1) ? Wk : Wv);
  int c0 = blockIdx.x * 32, h0 = blockIdx.y * 32;
  int tx = threadIdx.x, ty = threadIdx.y;  // 32 x 8
#pragma unroll
  for (int i = 0; i < 4; i++)
    tile[ty + 8 * i][tx] = W[(size_t)(c0 + ty + 8 * i) * H_ + h0 + tx];
  __syncthreads();
  size_t base = (size_t)m * H_ * C_;
#pragma unroll
  for (int i = 0; i < 4; i++) {
    float f = tile[tx][ty + 8 * i];
    unsigned short hi = f2bf(f);
    int h = h0 + ty + 8 * i;
    int kg = c0 + tx;
    int w0 = kg >> 6, c = (kg >> 3) & 7, e = kg & 7;
    size_t idx = base + (size_t)h * C_ + w0 * 64 + ((c + (h & 7)) & 7) * 8 + e;
    Whi[idx] = hi;
    if (m < 2) Wlo[idx] = f2bf(f - bf2f(hi));
  }
}

// ---------------------------------------------------------------------------
// Kernel 2: fused QKV projection, BK=64.  (unchanged)
// ---------------------------------------------------------------------------
__global__ __launch_bounds__(256, 3) void qkv_k(
    const float* __restrict__ x, const unsigned short* __restrict__ Whi,
    const unsigned short* __restrict__ Wlo, unsigned short* __restrict__ Qhi,
    unsigned short* __restrict__ Qlo, unsigned short* __restrict__ Khf,
    unsigned short* __restrict__ Klf, unsigned short* __restrict__ Vf) {
  int m = blockIdx.x % 3;
  int r0 = (blockIdx.x / 3) * 64;
  __shared__ __align__(16) float sx[64 * 64];            // 16 KB, row=256B swizzled
  __shared__ __align__(16) unsigned short swh[128 * 64]; // 16 KB, row=128B swizzled
  __shared__ __align__(16) unsigned short swl[128 * 64]; // 16 KB
  int tid = threadIdx.x;
  int lane = tid & 63, wave = tid >> 6;
  int l15 = lane & 15, quad = lane >> 4;
  const unsigned short* Wmh = Whi + (size_t)m * H_ * C_;
  const unsigned short* Wml = Wlo + (size_t)m * H_ * C_;
  f32x4 acc[8];
#pragma unroll
  for (int n = 0; n < 8; n++) acc[n] = (f32x4){0.f, 0.f, 0.f, 0.f};

  for (int k0 = 0; k0 < C_; k0 += 64) {
    __syncthreads();  // prior iter's LDS reads done
#pragma unroll
    for (int i = 0; i < 4; i++) {
      int s = (wave * 4 + i) * 64 + lane;
      {  // x: LDS slot (tr,p) <- x[r0+tr][k0 + ((p-tr)&15)*4]  (rotated gather)
        int tr = s >> 4, p = s & 15;
        async16((unsigned short*)sx + (size_t)(wave * 4 + i) * 512,
                x + (size_t)(r0 + tr) * C_ + k0 + ((p - tr) & 15) * 4);
      }
      {  // W: flat copy (global already rotated by wt_k)
        int hr = s >> 3, p = s & 7;
        async16(swh + (size_t)(wave * 4 + i) * 512,
                Wmh + (size_t)hr * C_ + k0 + p * 8);
        if (m < 2)
          async16(swl + (size_t)(wave * 4 + i) * 512,
                  Wml + (size_t)hr * C_ + k0 + p * 8);
      }
    }
    __syncthreads();  // barrier drains vmcnt -> staging visible
#pragma unroll
    for (int kk = 0; kk < 2; kk++) {
      float xa[8];
#pragma unroll
      for (int half = 0; half < 2; half++) {
        int p = (kk * 8 + quad * 2 + half + l15) & 15;
        *(f32x4*)&xa[half * 4] =
            *(const f32x4*)(const void*)(sx + (wave * 16 + l15) * 64 + p * 4);
      }
      bf16x8 ahi, alo;
      split8a(xa, ahi, alo);
      if (m < 2) {
#pragma unroll
        for (int n = 0; n < 8; n++) {
          int p = (kk * 4 + quad + l15) & 7;
          bf16x8 bhi = ldb8(swh + (n * 16 + l15) * 64 + p * 8);
          bf16x8 blo = ldb8(swl + (n * 16 + l15) * 64 + p * 8);
          acc[n] = __builtin_amdgcn_mfma_f32_16x16x32_bf16(ahi, bhi, acc[n], 0, 0, 0);
          acc[n] = __builtin_amdgcn_mfma_f32_16x16x32_bf16(alo, bhi, acc[n], 0, 0, 0);
          acc[n] = __builtin_amdgcn_mfma_f32_16x16x32_bf16(ahi, blo, acc[n], 0, 0, 0);
        }
      } else {
#pragma unroll
        for (int n = 0; n < 8; n++) {
          int p = (kk * 4 + quad + l15) & 7;
          bf16x8 bhi = ldb8(swh + (n * 16 + l15) * 64 + p * 8);
          acc[n] = __builtin_amdgcn_mfma_f32_16x16x32_bf16(ahi, bhi, acc[n], 0, 0, 0);
        }
      }
    }
  }
  // epilogue: C-layout row = quad*4+r, col = n8*16+l15
  int ob = r0 + wave * 16 + quad * 4;
  if (m == 0) {  // Q: linear hi/lo
#pragma unroll
    for (int n8 = 0; n8 < 8; n8++)
#pragma unroll
      for (int r = 0; r < 4; r++) {
        float f = acc[n8][r];
        unsigned short hi = f2bf(f);
        size_t idx = (size_t)(ob + r) * H_ + n8 * 16 + l15;
        Qhi[idx] = hi;
        Qlo[idx] = f2bf(f - bf2f(hi));
      }
  } else if (m == 1) {  // K: fragment order hi/lo
#pragma unroll
    for (int n8 = 0; n8 < 8; n8++)
#pragma unroll
      for (int r = 0; r < 4; r++) {
        int gr = ob + r;
        int bb = gr >> 12, t = gr & (T_ - 1);
        int kt = t >> 6, tr = t & 63, nf = tr >> 4, lk = tr & 15;
        int h = n8 * 16 + l15;
        int kkf = h >> 5, qk = (h >> 3) & 3, e = h & 7;
        size_t idx = (size_t)bb * T_ * H_ +
                     (size_t)((kt * 16 + nf * 4 + kkf) * 64 + qk * 16 + lk) * 8 + e;
        float f = acc[n8][r];
        unsigned short hi = f2bf(f);
        Khf[idx] = hi;
        Klf[idx] = f2bf(f - bf2f(hi));
      }
  } else {  // V: fragment order
#pragma unroll
    for (int n8 = 0; n8 < 8; n8++)
#pragma unroll
      for (int r = 0; r < 4; r++) {
        int gr = ob + r;
        int bb = gr >> 12, t = gr & (T_ - 1);
        int kt = t >> 6, ks = (t >> 5) & 1, qv = (t >> 3) & 3, jj = t & 7;
        size_t idx = (size_t)bb * T_ * H_ +
                     (size_t)((kt * 16 + ks * 8 + n8) * 64 + qv * 16 + l15) * 8 + jj;
        Vf[idx] = f2bf(acc[n8][r]);
      }
  }
}

// ---------------------------------------------------------------------------
// online softmax update for one 16-row tile (s[2] = 16x32 scores in C-layout)
// ---------------------------------------------------------------------------
__device__ __forceinline__ void online_sm(f32x4* s, float* mr, float* lr,
                                          f32x4* o) {
  float mnew[4];
#pragma unroll
  for (int r = 0; r < 4; r++) mnew[r] = fmaxf(s[0][r], s[1][r]);
#pragma unroll
  for (int off = 1; off < 16; off <<= 1)
#pragma unroll
    for (int r = 0; r < 4; r++) mnew[r] = fmaxf(mnew[r], __shfl_xor(mnew[r], off));
  float alpha[4];
#pragma unroll
  for (int r = 0; r < 4; r++) {
    float mi = fmaxf(mr[r], mnew[r]);
    alpha[r] = __expf(mr[r] - mi);
    mr[r] = mi;
  }
#pragma unroll
  for (int n16 = 0; n16 < 2; ++n16)
#pragma unroll
    for (int r = 0; r < 4; r++) s[n16][r] = __expf(s[n16][r] - mr[r]);
  float rs[4];
#pragma unroll
  for (int r = 0; r < 4; r++) rs[r] = s[0][r] + s[1][r];
#pragma unroll
  for (int off = 1; off < 16; off <<= 1)
#pragma unroll
    for (int r = 0; r < 4; r++) rs[r] += __shfl_xor(rs[r], off);
#pragma unroll
  for (int r = 0; r < 4; r++) lr[r] = lr[r] * alpha[r] + rs[r];
#pragma unroll
  for (int n = 0; n < 8; n++)
#pragma unroll
    for (int r = 0; r < 4; r++) o[n][r] *= alpha[r];
}

// ---------------------------------------------------------------------------
// Kernel 3: flash attention v3.
//  - block = 128 Q rows, 4 waves; wave w owns 32 rows = TWO 16-row MFMA tiles
//    -> K/V fragments read from LDS ONCE per wave, reused for both Q tiles
//    (LDS bytes per MFMA halved vs flash2 -- the measured bottleneck)
//  - KV step = 32 rows, Khi+Klo+V = 24KB tile, double-buffered LDS via
//    global_load_lds with counted vmcnt(6) (never 0 in loop)  [T3+T4]
//  - split-KV x4: q-block p, split s gets chunks [s(p+1),(s+1)(p+1)) -- all
//    splits exactly p+1 iters. 512 blocks total, 2/CU.
//  - LPT dispatch: p = 31-(n>>4) (strictly longest-first) -> every CU settles
//    at ~33 iterations (flash2's pairing gave CU0 96 vs CU255 34: the 11.4%
//    occupancy). g=n&15 decodes so each XCD touches ONE batch (3MB < L2).
// ---------------------------------------------------------------------------
#define PP2 40  // per-tile P-buffer pitch (u16): 16 rows x 32 cols + pad
__global__ __launch_bounds__(256, 2) void flash3_k(
    const unsigned short* __restrict__ Qhi, const unsigned short* __restrict__ Qlo,
    const unsigned short* __restrict__ Khf, const unsigned short* __restrict__ Klf,
    const unsigned short* __restrict__ Vf, float* __restrict__ opart,
    float2* __restrict__ mlpart) {
  __shared__ __align__(16) unsigned short skh[2][4096];     // 16 KB Khi dbuf
  __shared__ __align__(16) unsigned short skl[2][4096];     // 16 KB Klo dbuf
  __shared__ __align__(16) unsigned short sv[2][4096];      // 16 KB V   dbuf
  __shared__ __align__(16) unsigned short pb[4][2][16 * PP2];  // 10 KB P bufs
  int tid = threadIdx.x;
  int wave = tid >> 6, lane = tid & 63;
  int l15 = lane & 15, quad = lane >> 4;

  int n = blockIdx.x;            // 0..511
  int p = 31 - (n >> 4);         // 128-row q-tile index, longest-first (LPT)
  int g = n & 15;
  int sp = g >> 2, b = g & 3;    // XCD (n&7) sees only batch b = single batch
  int q0 = p << 7;
  int ktB = sp * (p + 1);        // first 32-row KV chunk of this split
  int nt = p + 1;                // chunks in this split (same for all splits)
  size_t boff = (size_t)b * T_ * H_;
  const unsigned short* Khb = Khf + boff;
  const unsigned short* Klb = Klf + boff;
  const unsigned short* Vb = Vf + boff;

  // Q fragments for this wave's two 16-row tiles
  bf16x8 qh0[4], ql0[4], qh1[4], ql1[4];
  {
    const unsigned short* qrh =
        Qhi + boff + (size_t)(q0 + wave * 32 + l15) * H_ + quad * 8;
    const unsigned short* qrl =
        Qlo + boff + (size_t)(q0 + wave * 32 + l15) * H_ + quad * 8;
#pragma unroll
    for (int kk = 0; kk < 4; kk++) {
      qh0[kk] = ldb8(qrh + kk * 32);
      ql0[kk] = ldb8(qrl + kk * 32);
      qh1[kk] = ldb8(qrh + 16 * H_ + kk * 32);
      ql1[kk] = ldb8(qrl + 16 * H_ + kk * 32);
    }
  }
  f32x4 o0[8], o1[8];
#pragma unroll
  for (int nn = 0; nn < 8; nn++) {
    o0[nn] = (f32x4){0.f, 0.f, 0.f, 0.f};
    o1[nn] = (f32x4){0.f, 0.f, 0.f, 0.f};
  }
  float mr0[4] = {-1e30f, -1e30f, -1e30f, -1e30f};
  float mr1[4] = {-1e30f, -1e30f, -1e30f, -1e30f};
  float lr0[4] = {0.f, 0.f, 0.f, 0.f};
  float lr1[4] = {0.f, 0.f, 0.f, 0.f};

  int rmin = q0 + wave * 32;  // tile0 first row; tile1 first row = rmin+16
  unsigned short* pb0 = pb[wave][0];
  unsigned short* pb1 = pb[wave][1];
  int ch = wave * 2;  // this wave's 2 staging chunks (of 8)

  // stage 32-row KV chunk kt32 into buffer d: 6 x 1KB DMA per wave
#define STAGE(kt32_, d_)                                                        \
  {                                                                             \
    size_t gbase = (size_t)(kt32_)*4096 + (size_t)ch * 512 + (size_t)lane * 8;  \
    async16(&skh[d_][ch * 512], Khb + gbase);                                   \
    async16(&skh[d_][(ch + 1) * 512], Khb + gbase + 512);                       \
    async16(&skl[d_][ch * 512], Klb + gbase);                                   \
    async16(&skl[d_][(ch + 1) * 512], Klb + gbase + 512);                       \
    async16(&sv[d_][ch * 512], Vb + gbase);                                     \
    async16(&sv[d_][(ch + 1) * 512], Vb + gbase + 512);                         \
  }

  STAGE(ktB, 0);
  int cur = 0;
  for (int it = 0; it < nt; ++it) {
    int kt32 = ktB + it;
    if (it + 1 < nt) {
      STAGE(kt32 + 1, cur ^ 1);  // issue next tile (6 loads stay in flight)
      asm volatile("s_waitcnt vmcnt(6)" ::: "memory");  // current tile done
    } else {
      asm volatile("s_waitcnt vmcnt(0)" ::: "memory");
    }
    __builtin_amdgcn_s_barrier();  // staging visible to all waves
    int c0k = kt32 << 5;
    bool t1a = (c0k <= rmin + 31);  // tile1 has unmasked rows (implies loads)
    bool t0a = (c0k <= rmin + 15);  // tile0 has unmasked rows
    if (t1a) {
      f32x4 s0[2], s1[2];
#pragma unroll
      for (int n16 = 0; n16 < 2; ++n16) {
        s0[n16] = (f32x4){0.f, 0.f, 0.f, 0.f};
        s1[n16] = (f32x4){0.f, 0.f, 0.f, 0.f};
      }
#pragma unroll
      for (int n16 = 0; n16 < 2; ++n16) {
        bf16x8 kh[4], kl[4];
#pragma unroll
        for (int kk = 0; kk < 4; kk++) {
          kh[kk] = ldb8(&skh[cur][(n16 * 4 + kk) * 512 + lane * 8]);
          kl[kk] = ldb8(&skl[cur][(n16 * 4 + kk) * 512 + lane * 8]);
        }
#pragma unroll
        for (int kk = 0; kk < 4; kk++) {  // K frags reused for BOTH Q tiles
          s0[n16] = __builtin_amdgcn_mfma_f32_16x16x32_bf16(qh0[kk], kh[kk], s0[n16], 0, 0, 0);
          s0[n16] = __builtin_amdgcn_mfma_f32_16x16x32_bf16(ql0[kk], kh[kk], s0[n16], 0, 0, 0);
          s0[n16] = __builtin_amdgcn_mfma_f32_16x16x32_bf16(qh0[kk], kl[kk], s0[n16], 0, 0, 0);
          s1[n16] = __builtin_amdgcn_mfma_f32_16x16x32_bf16(qh1[kk], kh[kk], s1[n16], 0, 0, 0);
          s1[n16] = __builtin_amdgcn_mfma_f32_16x16x32_bf16(ql1[kk], kh[kk], s1[n16], 0, 0, 0);
          s1[n16] = __builtin_amdgcn_mfma_f32_16x16x32_bf16(qh1[kk], kl[kk], s1[n16], 0, 0, 0);
        }
      }
      // causal mask (diagonal chunks only)
      if (c0k + 31 > rmin + 16) {
#pragma unroll
        for (int n16 = 0; n16 < 2; ++n16) {
          int col = c0k + n16 * 16 + l15;
#pragma unroll
          for (int r = 0; r < 4; r++)
            if (col > rmin + 16 + quad * 4 + r) s1[n16][r] = -1e30f;
        }
      }
      if (t0a && c0k + 31 > rmin) {
#pragma unroll
        for (int n16 = 0; n16 < 2; ++n16) {
          int col = c0k + n16 * 16 + l15;
#pragma unroll
          for (int r = 0; r < 4; r++)
            if (col > rmin + quad * 4 + r) s0[n16][r] = -1e30f;
        }
      }
      online_sm(s1, mr1, lr1, o1);
      if (t0a) online_sm(s0, mr0, lr0, o0);
      // P: C-layout -> A-layout via wave-private LDS (lgkm ordering suffices)
      asm volatile("s_waitcnt lgkmcnt(0)" ::: "memory");
#pragma unroll
      for (int n16 = 0; n16 < 2; ++n16)
#pragma unroll
        for (int r = 0; r < 4; r++)
          pb1[(quad * 4 + r) * PP2 + n16 * 16 + l15] = f2bf(s1[n16][r]);
      if (t0a) {
#pragma unroll
        for (int n16 = 0; n16 < 2; ++n16)
#pragma unroll
          for (int r = 0; r < 4; r++)
            pb0[(quad * 4 + r) * PP2 + n16 * 16 + l15] = f2bf(s0[n16][r]);
      }
      asm volatile("s_waitcnt lgkmcnt(0)" ::: "memory");
      bf16x8 pa1 = ldb8(pb1 + l15 * PP2 + quad * 8);  // k=32 A-fragment
      bf16x8 pa0;
      if (t0a) pa0 = ldb8(pb0 + l15 * PP2 + quad * 8);
#pragma unroll
      for (int nv = 0; nv < 8; ++nv) {  // V frags reused for BOTH Q tiles
        bf16x8 vf = ldb8(&sv[cur][nv * 512 + lane * 8]);
        o1[nv] = __builtin_amdgcn_mfma_f32_16x16x32_bf16(pa1, vf, o1[nv], 0, 0, 0);
        if (t0a)
          o0[nv] = __builtin_amdgcn_mfma_f32_16x16x32_bf16(pa0, vf, o0[nv], 0, 0, 0);
      }
    }
    __builtin_amdgcn_s_barrier();  // all waves done reading buf before reuse
    cur ^= 1;
  }
#undef STAGE

  // epilogue: unnormalized partials straight to workspace (no cross-wave work)
  size_t obase = (size_t)((b * 32 + p) * 4 + sp) * (128 * 128);
  size_t mbase = (size_t)((b * 32 + p) * 4 + sp) * 128;
  int wr0 = wave * 32 + quad * 4;
#pragma unroll
  for (int nn = 0; nn < 8; nn++)
#pragma unroll
    for (int r = 0; r < 4; r++) {
      opart[obase + (size_t)(wr0 + r) * 128 + nn * 16 + l15] = o0[nn][r];
      opart[obase + (size_t)(wr0 + 16 + r) * 128 + nn * 16 + l15] = o1[nn][r];
    }
  if (l15 == 0) {
#pragma unroll
    for (int r = 0; r < 4; r++) {
      mlpart[mbase + wr0 + r] = make_float2(mr0[r], lr0[r]);
      mlpart[mbase + wr0 + 16 + r] = make_float2(mr1[r], lr1[r]);
    }
  }
}

// ---------------------------------------------------------------------------
// Kernel 4: merge the four KV-splits. One thread = 8 output cols.
// ---------------------------------------------------------------------------
__global__ __launch_bounds__(256) void comb_k(const float* __restrict__ opart,
                                              const float2* __restrict__ mlpart,
                                              float* __restrict__ out) {
  int gid = blockIdx.x * 256 + threadIdx.x;  // 0 .. B*T*16-1
  int row = gid >> 4;
  int c0 = (gid & 15) << 3;
  int b = row >> 12, t = row & (T_ - 1);
  int p = t >> 7, r = t & 127;
  size_t base = (size_t)(b * 32 + p) * 4;  // (b,p) -> 4 splits
  float2 ml[4];
#pragma unroll
  for (int s = 0; s < 4; s++) ml[s] = mlpart[base * 128 + s * 128 + r];
  float M = fmaxf(fmaxf(ml[0].x, ml[1].x), fmaxf(ml[2].x, ml[3].x));
  float w[4], L = 0.f;
#pragma unroll
  for (int s = 0; s < 4; s++) {
    w[s] = __expf(ml[s].x - M);
    L += w[s] * ml[s].y;
  }
  float invL = 1.0f / L;
  f32x4 a0 = (f32x4){0.f, 0.f, 0.f, 0.f}, a1 = a0;
#pragma unroll
  for (int s = 0; s < 4; s++) {
    const float* src = opart + (base + s) * (128 * 128) + (size_t)r * 128 + c0;
    a0 += *(const f32x4*)(const void*)src * w[s];
    a1 += *(const f32x4*)(const void*)(src + 4) * w[s];
  }
  float* op = out + ((size_t)b * T_ + t) * H_ + c0;
  *(f32x4*)(void*)op = a0 * invL;
  *(f32x4*)(void*)(op + 4) = a1 * invL;
}

// ---------------------------------------------------------------------------
extern "C" void kernel_launch(void* const* d_in, const int* in_sizes, int n_in,
                              void* d_out, int out_size, void* d_ws, size_t ws_size,
                              hipStream_t stream) {
  const float* x  = (const float*)d_in[0];
  const float* Wq = (const float*)d_in[1];
  const float* Wk = (const float*)d_in[2];
  const float* Wv = (const float*)d_in[3];
  const size_t BTH = (size_t)B_ * T_ * H_;
  unsigned short* Whi = (unsigned short*)d_ws;   // 3*H*C
  unsigned short* Wlo = Whi + 3 * H_ * C_;       // 2*H*C (Q,K only)
  unsigned short* Vf  = Wlo + 2 * H_ * C_;       // BTH
  unsigned short* Qhi = Vf + BTH;
  unsigned short* Qlo = Qhi + BTH;
  unsigned short* Khf = Qlo + BTH;
  unsigned short* Klf = Khf + BTH;
  float* opart = (float*)(void*)(Klf + BTH);     // 4 splits * BTH f32 (33.5MB)
  float2* mlpart = (float2*)(void*)(opart + 4 * BTH);
  float* out = (float*)d_out;

  wt_k<<<dim3(32, 4, 3), dim3(32, 8), 0, stream>>>(Wq, Wk, Wv, Whi, Wlo);
  qkv_k<<<3 * (B_ * T_ / 64), 256, 0, stream>>>(x, Whi, Wlo, Qhi, Qlo, Khf, Klf, Vf);
  flash3_k<<<512, 256, 0, stream>>>(Qhi, Qlo, Khf, Klf, Vf, opart, mlpart);
  comb_k<<<(B_ * T_ * 16) / 256, 256, 0, stream>>>(opart, mlpart, out);
}

// Round 4
// 221.794 us; speedup vs baseline: 1.2794x; 1.0798x over previous
//
#include <hip/hip_runtime.h>

#define B_ 4
#define T_ 4096
#define C_ 1024
#define H_ 128

typedef __attribute__((ext_vector_type(8))) __bf16 bf16x8;
typedef __attribute__((ext_vector_type(8))) unsigned short u16x8;
typedef __attribute__((ext_vector_type(4))) float f32x4;
typedef __attribute__((ext_vector_type(4))) unsigned int u32x4;

__device__ __forceinline__ unsigned short f2bf(float f) {
  unsigned int u = __float_as_uint(f);
  return (unsigned short)((u + 0x7FFFu + ((u >> 16) & 1u)) >> 16);
}
__device__ __forceinline__ float bf2f(unsigned short h) {
  return __uint_as_float((unsigned)h << 16);
}
__device__ __forceinline__ bf16x8 ldb8(const unsigned short* p) {
  return *(const bf16x8*)(const void*)p;
}
// async global->LDS DMA: 16B/lane, LDS dest = wave-uniform base + lane*16
__device__ __forceinline__ void async16(void* lds, const void* g) {
  __builtin_amdgcn_global_load_lds(
      (const __attribute__((address_space(1))) unsigned int*)g,
      (__attribute__((address_space(3))) unsigned int*)lds, 16, 0, 0);
}
__device__ __forceinline__ void split8a(const float* f, bf16x8& hi, bf16x8& lo) {
  u16x8 h, l;
#pragma unroll
  for (int j = 0; j < 8; j++) {
    h[j] = f2bf(f[j]);
    l[j] = f2bf(f[j] - bf2f(h[j]));
  }
  hi = __builtin_bit_cast(bf16x8, h);
  lo = __builtin_bit_cast(bf16x8, l);
}

// Fragment-ordered K/V global layouts (per batch, elem offsets):
//   K(t,h): kt=t>>6 n=(t>>4)&3 lk=t&15 kk=h>>5 qk=(h>>3)&3 e=h&7
//           off = ((kt*16+n*4+kk)*64 + qk*16+lk)*8 + e
//   V(t,h): kt=t>>6 ks=(t>>5)&1 qv=(t>>3)&3 j=t&7 nv=h>>4 lv=h&15
//           off = ((kt*16+ks*8+nv)*64 + qv*16+lv)*8 + j
// => a 32-row KV chunk kt32 is elems [kt32*4096, kt32*4096+4096): CONTIGUOUS.
//    flash4 stages it into LDS as a linear 8KB copy (6 x async16/thread for
//    Khi+Klo+V) and reads fragments at frag*1KB + lane*16B (conflict-free).

// ---------------------------------------------------------------------------
// Kernel 1: W [C][H] fp32 -> Wthi/Wtlo [.][H][C] bf16, transpose + split.
// (unchanged)
// ---------------------------------------------------------------------------
__global__ void wt_k(const float* __restrict__ Wq, const float* __restrict__ Wk,
                     const float* __restrict__ Wv, unsigned short* __restrict__ Whi,
                     unsigned short* __restrict__ Wlo) {
  __shared__ float tile[32][33];
  int m = blockIdx.z;
  const float* W = (m == 0) ? Wq : ((m == 1) ? Wk : Wv);
  int c0 = blockIdx.x * 32, h0 = blockIdx.y * 32;
  int tx = threadIdx.x, ty = threadIdx.y;  // 32 x 8
#pragma unroll
  for (int i = 0; i < 4; i++)
    tile[ty + 8 * i][tx] = W[(size_t)(c0 + ty + 8 * i) * H_ + h0 + tx];
  __syncthreads();
  size_t base = (size_t)m * H_ * C_;
#pragma unroll
  for (int i = 0; i < 4; i++) {
    float f = tile[tx][ty + 8 * i];
    unsigned short hi = f2bf(f);
    int h = h0 + ty + 8 * i;
    int kg = c0 + tx;
    int w0 = kg >> 6, c = (kg >> 3) & 7, e = kg & 7;
    size_t idx = base + (size_t)h * C_ + w0 * 64 + ((c + (h & 7)) & 7) * 8 + e;
    Whi[idx] = hi;
    if (m < 2) Wlo[idx] = f2bf(f - bf2f(hi));
  }
}

// ---------------------------------------------------------------------------
// Kernel 2: fused QKV projection, BK=64.  (unchanged)
// ---------------------------------------------------------------------------
__global__ __launch_bounds__(256, 3) void qkv_k(
    const float* __restrict__ x, const unsigned short* __restrict__ Whi,
    const unsigned short* __restrict__ Wlo, unsigned short* __restrict__ Qhi,
    unsigned short* __restrict__ Qlo, unsigned short* __restrict__ Khf,
    unsigned short* __restrict__ Klf, unsigned short* __restrict__ Vf) {
  int m = blockIdx.x % 3;
  int r0 = (blockIdx.x / 3) * 64;
  __shared__ __align__(16) float sx[64 * 64];            // 16 KB, row=256B swizzled
  __shared__ __align__(16) unsigned short swh[128 * 64]; // 16 KB, row=128B swizzled
  __shared__ __align__(16) unsigned short swl[128 * 64]; // 16 KB
  int tid = threadIdx.x;
  int lane = tid & 63, wave = tid >> 6;
  int l15 = lane & 15, quad = lane >> 4;
  const unsigned short* Wmh = Whi + (size_t)m * H_ * C_;
  const unsigned short* Wml = Wlo + (size_t)m * H_ * C_;
  f32x4 acc[8];
#pragma unroll
  for (int n = 0; n < 8; n++) acc[n] = (f32x4){0.f, 0.f, 0.f, 0.f};

  for (int k0 = 0; k0 < C_; k0 += 64) {
    __syncthreads();  // prior iter's LDS reads done
#pragma unroll
    for (int i = 0; i < 4; i++) {
      int s = (wave * 4 + i) * 64 + lane;
      {  // x: LDS slot (tr,p) <- x[r0+tr][k0 + ((p-tr)&15)*4]  (rotated gather)
        int tr = s >> 4, p = s & 15;
        async16((unsigned short*)sx + (size_t)(wave * 4 + i) * 512,
                x + (size_t)(r0 + tr) * C_ + k0 + ((p - tr) & 15) * 4);
      }
      {  // W: flat copy (global already rotated by wt_k)
        int hr = s >> 3, p = s & 7;
        async16(swh + (size_t)(wave * 4 + i) * 512,
                Wmh + (size_t)hr * C_ + k0 + p * 8);
        if (m < 2)
          async16(swl + (size_t)(wave * 4 + i) * 512,
                  Wml + (size_t)hr * C_ + k0 + p * 8);
      }
    }
    __syncthreads();  // barrier drains vmcnt -> staging visible
#pragma unroll
    for (int kk = 0; kk < 2; kk++) {
      float xa[8];
#pragma unroll
      for (int half = 0; half < 2; half++) {
        int p = (kk * 8 + quad * 2 + half + l15) & 15;
        *(f32x4*)&xa[half * 4] =
            *(const f32x4*)(const void*)(sx + (wave * 16 + l15) * 64 + p * 4);
      }
      bf16x8 ahi, alo;
      split8a(xa, ahi, alo);
      if (m < 2) {
#pragma unroll
        for (int n = 0; n < 8; n++) {
          int p = (kk * 4 + quad + l15) & 7;
          bf16x8 bhi = ldb8(swh + (n * 16 + l15) * 64 + p * 8);
          bf16x8 blo = ldb8(swl + (n * 16 + l15) * 64 + p * 8);
          acc[n] = __builtin_amdgcn_mfma_f32_16x16x32_bf16(ahi, bhi, acc[n], 0, 0, 0);
          acc[n] = __builtin_amdgcn_mfma_f32_16x16x32_bf16(alo, bhi, acc[n], 0, 0, 0);
          acc[n] = __builtin_amdgcn_mfma_f32_16x16x32_bf16(ahi, blo, acc[n], 0, 0, 0);
        }
      } else {
#pragma unroll
        for (int n = 0; n < 8; n++) {
          int p = (kk * 4 + quad + l15) & 7;
          bf16x8 bhi = ldb8(swh + (n * 16 + l15) * 64 + p * 8);
          acc[n] = __builtin_amdgcn_mfma_f32_16x16x32_bf16(ahi, bhi, acc[n], 0, 0, 0);
        }
      }
    }
  }
  // epilogue: C-layout row = quad*4+r, col = n8*16+l15
  int ob = r0 + wave * 16 + quad * 4;
  if (m == 0) {  // Q: linear hi/lo
#pragma unroll
    for (int n8 = 0; n8 < 8; n8++)
#pragma unroll
      for (int r = 0; r < 4; r++) {
        float f = acc[n8][r];
        unsigned short hi = f2bf(f);
        size_t idx = (size_t)(ob + r) * H_ + n8 * 16 + l15;
        Qhi[idx] = hi;
        Qlo[idx] = f2bf(f - bf2f(hi));
      }
  } else if (m == 1) {  // K: fragment order hi/lo
#pragma unroll
    for (int n8 = 0; n8 < 8; n8++)
#pragma unroll
      for (int r = 0; r < 4; r++) {
        int gr = ob + r;
        int bb = gr >> 12, t = gr & (T_ - 1);
        int kt = t >> 6, tr = t & 63, nf = tr >> 4, lk = tr & 15;
        int h = n8 * 16 + l15;
        int kkf = h >> 5, qk = (h >> 3) & 3, e = h & 7;
        size_t idx = (size_t)bb * T_ * H_ +
                     (size_t)((kt * 16 + nf * 4 + kkf) * 64 + qk * 16 + lk) * 8 + e;
        float f = acc[n8][r];
        unsigned short hi = f2bf(f);
        Khf[idx] = hi;
        Klf[idx] = f2bf(f - bf2f(hi));
      }
  } else {  // V: fragment order
#pragma unroll
    for (int n8 = 0; n8 < 8; n8++)
#pragma unroll
      for (int r = 0; r < 4; r++) {
        int gr = ob + r;
        int bb = gr >> 12, t = gr & (T_ - 1);
        int kt = t >> 6, ks = (t >> 5) & 1, qv = (t >> 3) & 3, jj = t & 7;
        size_t idx = (size_t)bb * T_ * H_ +
                     (size_t)((kt * 16 + ks * 8 + n8) * 64 + qv * 16 + l15) * 8 + jj;
        Vf[idx] = f2bf(acc[n8][r]);
      }
  }
}

// ---------------------------------------------------------------------------
// Swapped-QK softmax for one 16-row tile.
// Input s[2] = S^T fragments: lane (l15,quad) holds S[qrow=l15][k=n16*16+quad*4+r].
// Updates scalar (m,l), rescales o (C-layout rows quad*4+r via 4-shfl alpha
// broadcast), and returns the PV A-fragment of P built IN-REGISTER:
// A-word[a] = pack(n16=q_t>>1, j=a&1) pulled from lane (2(q_t&1)+(a>>1))*16+l15.
// (element-wise verified for lanes 0/17/32/48)
// ---------------------------------------------------------------------------
__device__ __forceinline__ bf16x8 sm_tile(f32x4* s, float& mr, float& lr,
                                          f32x4* o, int lane) {
  int l15 = lane & 15, quad = lane >> 4;
  float mx = fmaxf(fmaxf(fmaxf(s[0][0], s[0][1]), fmaxf(s[0][2], s[0][3])),
                   fmaxf(fmaxf(s[1][0], s[1][1]), fmaxf(s[1][2], s[1][3])));
  mx = fmaxf(mx, __shfl_xor(mx, 16));
  mx = fmaxf(mx, __shfl_xor(mx, 32));
  float mi = fmaxf(mr, mx);
  float al = __expf(mr - mi);
  mr = mi;
#pragma unroll
  for (int n16 = 0; n16 < 2; n16++)
#pragma unroll
    for (int r = 0; r < 4; r++) s[n16][r] = __expf(s[n16][r] - mi);
  float sum = ((s[0][0] + s[0][1]) + (s[0][2] + s[0][3])) +
              ((s[1][0] + s[1][1]) + (s[1][2] + s[1][3]));
  sum += __shfl_xor(sum, 16);
  sum += __shfl_xor(sum, 32);
  lr = lr * al + sum;
  float alo[4];
#pragma unroll
  for (int r = 0; r < 4; r++) alo[r] = __shfl(al, quad * 4 + r);
#pragma unroll
  for (int nv = 0; nv < 8; nv++)
#pragma unroll
    for (int r = 0; r < 4; r++) o[nv][r] *= alo[r];
  unsigned W[2][2];
#pragma unroll
  for (int n16 = 0; n16 < 2; n16++)
#pragma unroll
    for (int j = 0; j < 2; j++)
      W[n16][j] = (unsigned)f2bf(s[n16][2 * j]) |
                  ((unsigned)f2bf(s[n16][2 * j + 1]) << 16);
  int base = ((lane >> 4) & 1) * 32 + l15;
  unsigned A[4];
#pragma unroll
  for (int a = 0; a < 4; a++) {
    int src = base + (a >> 1) * 16;
    unsigned lo = (unsigned)__shfl((int)W[0][a & 1], src);
    unsigned hi = (unsigned)__shfl((int)W[1][a & 1], src);
    A[a] = (lane & 32) ? hi : lo;
  }
  u32x4 aw = (u32x4){A[0], A[1], A[2], A[3]};
  return __builtin_bit_cast(bf16x8, aw);
}

// ---------------------------------------------------------------------------
// Kernel 3: flash attention v4.
//  - BALANCED static pairing: blocks n and n+256 co-reside on one CU
//    (round-robin over 8 XCDs x 32 CUs); p(n)+p(n+256)=31 -> every CU gets
//    exactly 33 iterations (v3's mapping gave CU0=48 vs CU255=18 -> the
//    persistent 11.8% occupancy).
//  - swapped QK^T: S^T = mfma(K,Q). Row-reduce = 2 shfl steps (was 4);
//    P->A-fragment rebuilt in-register (8 shfl + packs); the P LDS buffer,
//    both lgkmcnt(0) drains, 16 ds_writes and 2 ds_reads per iter are GONE.
//    m/l are scalars per lane. LDS = 48KB.
//  - s_setprio(1) around MFMA clusters (T5; 2 independent blocks/CU).
//  - KV step 32 rows, dbuf LDS via global_load_lds, counted vmcnt(6).
//  - split-KV x4, partials merged by comb_k (unchanged).
// ---------------------------------------------------------------------------
__global__ __launch_bounds__(256, 2) void flash4_k(
    const unsigned short* __restrict__ Qhi, const unsigned short* __restrict__ Qlo,
    const unsigned short* __restrict__ Khf, const unsigned short* __restrict__ Klf,
    const unsigned short* __restrict__ Vf, float* __restrict__ opart,
    float2* __restrict__ mlpart) {
  __shared__ __align__(16) unsigned short skh[2][4096];  // 16 KB Khi dbuf
  __shared__ __align__(16) unsigned short skl[2][4096];  // 16 KB Klo dbuf
  __shared__ __align__(16) unsigned short sv[2][4096];   // 16 KB V   dbuf
  int tid = threadIdx.x;
  int wave = tid >> 6, lane = tid & 63;
  int l15 = lane & 15, quad = lane >> 4;

  int n = blockIdx.x;  // 0..511
  int h = n >> 4;
  int p = (h < 16) ? (31 - h) : (h - 16);  // balanced pairing: p(n)+p(n+256)=31
  int g = n & 15;
  int sp = g >> 2, b = g & 3;  // XCD (n&7) sees only batch b = (n&7)&3
  int q0 = p << 7;
  int ktB = sp * (p + 1);  // first 32-row KV chunk of this split
  int nt = p + 1;          // chunks in this split (same for all splits)
  size_t boff = (size_t)b * T_ * H_;
  const unsigned short* Khb = Khf + boff;
  const unsigned short* Klb = Klf + boff;
  const unsigned short* Vb = Vf + boff;

  // Q fragments for this wave's two 16-row tiles (B-operand layout)
  bf16x8 qh0[4], ql0[4], qh1[4], ql1[4];
  {
    const unsigned short* qrh =
        Qhi + boff + (size_t)(q0 + wave * 32 + l15) * H_ + quad * 8;
    const unsigned short* qrl =
        Qlo + boff + (size_t)(q0 + wave * 32 + l15) * H_ + quad * 8;
#pragma unroll
    for (int kk = 0; kk < 4; kk++) {
      qh0[kk] = ldb8(qrh + kk * 32);
      ql0[kk] = ldb8(qrl + kk * 32);
      qh1[kk] = ldb8(qrh + 16 * H_ + kk * 32);
      ql1[kk] = ldb8(qrl + 16 * H_ + kk * 32);
    }
  }
  f32x4 o0[8], o1[8];
#pragma unroll
  for (int nn = 0; nn < 8; nn++) {
    o0[nn] = (f32x4){0.f, 0.f, 0.f, 0.f};
    o1[nn] = (f32x4){0.f, 0.f, 0.f, 0.f};
  }
  float mr0 = -1e30f, mr1 = -1e30f, lr0 = 0.f, lr1 = 0.f;

  int rmin = q0 + wave * 32;  // tile0 first row; tile1 first row = rmin+16
  int ch = wave * 2;          // this wave's 2 staging chunks (of 8)

  // stage 32-row KV chunk kt32 into buffer d: 6 x 1KB DMA per wave
#define STAGE(kt32_, d_)                                                        \
  {                                                                             \
    size_t gbase = (size_t)(kt32_)*4096 + (size_t)ch * 512 + (size_t)lane * 8;  \
    async16(&skh[d_][ch * 512], Khb + gbase);                                   \
    async16(&skh[d_][(ch + 1) * 512], Khb + gbase + 512);                       \
    async16(&skl[d_][ch * 512], Klb + gbase);                                   \
    async16(&skl[d_][(ch + 1) * 512], Klb + gbase + 512);                       \
    async16(&sv[d_][ch * 512], Vb + gbase);                                     \
    async16(&sv[d_][(ch + 1) * 512], Vb + gbase + 512);                         \
  }

  STAGE(ktB, 0);
  int cur = 0;
  for (int it = 0; it < nt; ++it) {
    int kt32 = ktB + it;
    if (it + 1 < nt) {
      STAGE(kt32 + 1, cur ^ 1);  // issue next tile (6 loads stay in flight)
      asm volatile("s_waitcnt vmcnt(6)" ::: "memory");  // current tile done
    } else {
      asm volatile("s_waitcnt vmcnt(0)" ::: "memory");
    }
    __builtin_amdgcn_s_barrier();  // staging visible to all waves
    int c0k = kt32 << 5;
    bool t1a = (c0k <= rmin + 31);  // tile1 has unmasked rows
    bool t0a = (c0k <= rmin + 15);  // tile0 has unmasked rows
    if (t1a) {
      f32x4 s0[2], s1[2];
#pragma unroll
      for (int n16 = 0; n16 < 2; ++n16) {
        s0[n16] = (f32x4){0.f, 0.f, 0.f, 0.f};
        s1[n16] = (f32x4){0.f, 0.f, 0.f, 0.f};
      }
      __builtin_amdgcn_s_setprio(1);
#pragma unroll
      for (int n16 = 0; n16 < 2; ++n16) {
        bf16x8 kh[4], kl[4];
#pragma unroll
        for (int kk = 0; kk < 4; kk++) {
          kh[kk] = ldb8(&skh[cur][(n16 * 4 + kk) * 512 + lane * 8]);
          kl[kk] = ldb8(&skl[cur][(n16 * 4 + kk) * 512 + lane * 8]);
        }
#pragma unroll
        for (int kk = 0; kk < 4; kk++) {  // SWAPPED operands: S^T = K x Q
          s1[n16] = __builtin_amdgcn_mfma_f32_16x16x32_bf16(kh[kk], qh1[kk], s1[n16], 0, 0, 0);
          s1[n16] = __builtin_amdgcn_mfma_f32_16x16x32_bf16(kh[kk], ql1[kk], s1[n16], 0, 0, 0);
          s1[n16] = __builtin_amdgcn_mfma_f32_16x16x32_bf16(kl[kk], qh1[kk], s1[n16], 0, 0, 0);
          if (t0a) {
            s0[n16] = __builtin_amdgcn_mfma_f32_16x16x32_bf16(kh[kk], qh0[kk], s0[n16], 0, 0, 0);
            s0[n16] = __builtin_amdgcn_mfma_f32_16x16x32_bf16(kh[kk], ql0[kk], s0[n16], 0, 0, 0);
            s0[n16] = __builtin_amdgcn_mfma_f32_16x16x32_bf16(kl[kk], qh0[kk], s0[n16], 0, 0, 0);
          }
        }
      }
      __builtin_amdgcn_s_setprio(0);
      // causal mask (diagonal chunks only); score (qrow,kcol):
      //   kcol = c0k + n16*16 + quad*4 + r, qrow = rmin + t*16 + l15
      if (c0k + 31 > rmin + 16) {
        int row1 = rmin + 16 + l15;
#pragma unroll
        for (int n16 = 0; n16 < 2; ++n16)
#pragma unroll
          for (int r = 0; r < 4; r++) {
            int col = c0k + n16 * 16 + quad * 4 + r;
            if (col > row1) s1[n16][r] = -1e30f;
          }
      }
      if (t0a && c0k + 31 > rmin) {
        int row0 = rmin + l15;
#pragma unroll
        for (int n16 = 0; n16 < 2; ++n16)
#pragma unroll
          for (int r = 0; r < 4; r++) {
            int col = c0k + n16 * 16 + quad * 4 + r;
            if (col > row0) s0[n16][r] = -1e30f;
          }
      }
      bf16x8 pa1 = sm_tile(s1, mr1, lr1, o1, lane);
      bf16x8 pa0;
      if (t0a) pa0 = sm_tile(s0, mr0, lr0, o0, lane);
      __builtin_amdgcn_s_setprio(1);
#pragma unroll
      for (int nv = 0; nv < 8; ++nv) {  // V frags reused for BOTH Q tiles
        bf16x8 vf = ldb8(&sv[cur][nv * 512 + lane * 8]);
        o1[nv] = __builtin_amdgcn_mfma_f32_16x16x32_bf16(pa1, vf, o1[nv], 0, 0, 0);
        if (t0a)
          o0[nv] = __builtin_amdgcn_mfma_f32_16x16x32_bf16(pa0, vf, o0[nv], 0, 0, 0);
      }
      __builtin_amdgcn_s_setprio(0);
    }
    __builtin_amdgcn_s_barrier();  // all waves done reading buf before reuse
    cur ^= 1;
  }
#undef STAGE

  // epilogue: unnormalized partials straight to workspace
  size_t obase = (size_t)((b * 32 + p) * 4 + sp) * (128 * 128);
  size_t mbase = (size_t)((b * 32 + p) * 4 + sp) * 128;
  int wr0 = wave * 32 + quad * 4;
#pragma unroll
  for (int nn = 0; nn < 8; nn++)
#pragma unroll
    for (int r = 0; r < 4; r++) {
      opart[obase + (size_t)(wr0 + r) * 128 + nn * 16 + l15] = o0[nn][r];
      opart[obase + (size_t)(wr0 + 16 + r) * 128 + nn * 16 + l15] = o1[nn][r];
    }
  if (quad == 0) {  // m/l live at lane row=l15 (all quads identical)
    mlpart[mbase + wave * 32 + l15] = make_float2(mr0, lr0);
    mlpart[mbase + wave * 32 + 16 + l15] = make_float2(mr1, lr1);
  }
}

// ---------------------------------------------------------------------------
// Kernel 4: merge the four KV-splits. One thread = 8 output cols. (unchanged)
// ---------------------------------------------------------------------------
__global__ __launch_bounds__(256) void comb_k(const float* __restrict__ opart,
                                              const float2* __restrict__ mlpart,
                                              float* __restrict__ out) {
  int gid = blockIdx.x * 256 + threadIdx.x;  // 0 .. B*T*16-1
  int row = gid >> 4;
  int c0 = (gid & 15) << 3;
  int b = row >> 12, t = row & (T_ - 1);
  int p = t >> 7, r = t & 127;
  size_t base = (size_t)(b * 32 + p) * 4;  // (b,p) -> 4 splits
  float2 ml[4];
#pragma unroll
  for (int s = 0; s < 4; s++) ml[s] = mlpart[base * 128 + s * 128 + r];
  float M = fmaxf(fmaxf(ml[0].x, ml[1].x), fmaxf(ml[2].x, ml[3].x));
  float w[4], L = 0.f;
#pragma unroll
  for (int s = 0; s < 4; s++) {
    w[s] = __expf(ml[s].x - M);
    L += w[s] * ml[s].y;
  }
  float invL = 1.0f / L;
  f32x4 a0 = (f32x4){0.f, 0.f, 0.f, 0.f}, a1 = a0;
#pragma unroll
  for (int s = 0; s < 4; s++) {
    const float* src = opart + (base + s) * (128 * 128) + (size_t)r * 128 + c0;
    a0 += *(const f32x4*)(const void*)src * w[s];
    a1 += *(const f32x4*)(const void*)(src + 4) * w[s];
  }
  float* op = out + ((size_t)b * T_ + t) * H_ + c0;
  *(f32x4*)(void*)op = a0 * invL;
  *(f32x4*)(void*)(op + 4) = a1 * invL;
}

// ---------------------------------------------------------------------------
extern "C" void kernel_launch(void* const* d_in, const int* in_sizes, int n_in,
                              void* d_out, int out_size, void* d_ws, size_t ws_size,
                              hipStream_t stream) {
  const float* x  = (const float*)d_in[0];
  const float* Wq = (const float*)d_in[1];
  const float* Wk = (const float*)d_in[2];
  const float* Wv = (const float*)d_in[3];
  const size_t BTH = (size_t)B_ * T_ * H_;
  unsigned short* Whi = (unsigned short*)d_ws;   // 3*H*C
  unsigned short* Wlo = Whi + 3 * H_ * C_;       // 2*H*C (Q,K only)
  unsigned short* Vf  = Wlo + 2 * H_ * C_;       // BTH
  unsigned short* Qhi = Vf + BTH;
  unsigned short* Qlo = Qhi + BTH;
  unsigned short* Khf = Qlo + BTH;
  unsigned short* Klf = Khf + BTH;
  float* opart = (float*)(void*)(Klf + BTH);     // 4 splits * BTH f32 (33.5MB)
  float2* mlpart = (float2*)(void*)(opart + 4 * BTH);
  float* out = (float*)d_out;

  wt_k<<<dim3(32, 4, 3), dim3(32, 8), 0, stream>>>(Wq, Wk, Wv, Whi, Wlo);
  qkv_k<<<3 * (B_ * T_ / 64), 256, 0, stream>>>(x, Whi, Wlo, Qhi, Qlo, Khf, Klf, Vf);
  flash4_k<<<512, 256, 0, stream>>>(Qhi, Qlo, Khf, Klf, Vf, opart, mlpart);
  comb_k<<<(B_ * T_ * 16) / 256, 256, 0, stream>>>(opart, mlpart, out);
}